// Round 4
// baseline (665.982 us; speedup 1.0000x reference)
//
#include <hip/hip_runtime.h>
#include <hip/hip_bf16.h>
#include <math.h>

#define HID   128
#define TPB   256      // 4 waves per block, 16 rows per wave -> 64 rows per block-tile
#define TROWS 64
#define NBLK  1024     // persistent grid (4 blocks/CU)

typedef __attribute__((ext_vector_type(8))) short        short8v;   // 8 bf16
typedef __attribute__((ext_vector_type(4))) float        f32x4;
typedef __attribute__((ext_vector_type(4))) unsigned int uint4v;

#define MFMA(a, b, c) __builtin_amdgcn_mfma_f32_16x16x32_bf16((a), (b), (c), 0, 0, 0)

__device__ __forceinline__ unsigned int pk2bf(float lo, float hi) {
    unsigned short a = __builtin_bit_cast(unsigned short, __float2bfloat16(lo));
    unsigned short b = __builtin_bit_cast(unsigned short, __float2bfloat16(hi));
    return (unsigned int)a | ((unsigned int)b << 16);
}
__device__ __forceinline__ f32x4 relu4(f32x4 v) {
    f32x4 r;
    r.x = fmaxf(v.x, 0.f); r.y = fmaxf(v.y, 0.f);
    r.z = fmaxf(v.z, 0.f); r.w = fmaxf(v.w, 0.f);
    return r;
}

__global__ __launch_bounds__(TPB, 4)
void stress_kernel(const float* __restrict__ F,
                   const float* __restrict__ W1, const float* __restrict__ b1,
                   const float* __restrict__ W2, const float* __restrict__ b2,
                   const float* __restrict__ W3, const float* __restrict__ b3,
                   float* __restrict__ out, int N)
{
    // ---- LDS: constant, fragment-ordered weights (38.5 KB -> 4 blocks/CU) ----
    __shared__ uint4v sA2[2048];   // 32 KB  W2^T A-frags: [(jt*4+ks)*64 + lane]
    __shared__ uint4v sA3[256];    //  4 KB  W3^T A-frags: [ks2*64 + lane]
    __shared__ __align__(16) float sW1[3 * HID];
    __shared__ __align__(16) float sb1[HID];
    __shared__ __align__(16) float sb2[HID];

    const int tid  = threadIdx.x;
    const int lane = tid & 63;
    const int wid  = tid >> 6;
    const int g    = lane >> 4;     // lane group 0..3
    const int lr   = lane & 15;

    // ---- one-time per-block weight staging / swizzling ----
    // A2: value(lane,b,ks,jt) = bf16( W2[k][j] ), k = 8g+b+32ks, j = lr+16jt
    for (int e = tid; e < 2048; e += TPB) {
        int l = e & 63, ks = (e >> 6) & 3, jt = e >> 8;
        int k0 = 8 * (l >> 4) + 32 * ks;
        int j  = (l & 15) + 16 * jt;
        uint4v v;
        v.x = pk2bf(W2[(k0 + 0) * HID + j], W2[(k0 + 1) * HID + j]);
        v.y = pk2bf(W2[(k0 + 2) * HID + j], W2[(k0 + 3) * HID + j]);
        v.z = pk2bf(W2[(k0 + 4) * HID + j], W2[(k0 + 5) * HID + j]);
        v.w = pk2bf(W2[(k0 + 6) * HID + j], W2[(k0 + 7) * HID + j]);
        sA2[e] = v;
    }
    // A3: row t = lr (pad t>=4 with 0), slot (g,b,ks2) -> j = 4g+(b&3)+16*(2ks2+(b>>2))
    for (int e = tid; e < 256; e += TPB) {
        int l = e & 63, ks2 = e >> 6;
        int gg = l >> 4, t = l & 15;
        float w0  = (t < 4) ? W3[(4 * gg + 0 + 16 * (2 * ks2 + 0)) * 4 + t] : 0.f;
        float w1_ = (t < 4) ? W3[(4 * gg + 1 + 16 * (2 * ks2 + 0)) * 4 + t] : 0.f;
        float w2_ = (t < 4) ? W3[(4 * gg + 2 + 16 * (2 * ks2 + 0)) * 4 + t] : 0.f;
        float w3_ = (t < 4) ? W3[(4 * gg + 3 + 16 * (2 * ks2 + 0)) * 4 + t] : 0.f;
        float w4  = (t < 4) ? W3[(4 * gg + 0 + 16 * (2 * ks2 + 1)) * 4 + t] : 0.f;
        float w5  = (t < 4) ? W3[(4 * gg + 1 + 16 * (2 * ks2 + 1)) * 4 + t] : 0.f;
        float w6  = (t < 4) ? W3[(4 * gg + 2 + 16 * (2 * ks2 + 1)) * 4 + t] : 0.f;
        float w7  = (t < 4) ? W3[(4 * gg + 3 + 16 * (2 * ks2 + 1)) * 4 + t] : 0.f;
        uint4v v;
        v.x = pk2bf(w0, w1_); v.y = pk2bf(w2_, w3_);
        v.z = pk2bf(w4, w5);  v.w = pk2bf(w6, w7);
        sA3[e] = v;
    }
    for (int i = tid; i < 3 * HID; i += TPB) sW1[i] = W1[i];
    for (int i = tid; i < HID; i += TPB)     { sb1[i] = b1[i]; sb2[i] = b2[i]; }
    __syncthreads();

    // typed LDS vector views
    const f32x4* pW1 = (const f32x4*)sW1;   // pW1[i*32 + k/4] = W1[i][k..k+3]
    const f32x4* pB1 = (const f32x4*)sb1;
    const f32x4* pB2 = (const f32x4*)sb2;

    const int nTiles = (N + TROWS - 1) / TROWS;
    for (int tile = blockIdx.x; tile < nTiles; tile += gridDim.x) {
        const int n = tile * TROWS + wid * 16 + lr;   // row owned by lanes 0..15 (g==0)

        // ---- prologue: lanes 0..15 load F, compute invariants + polar R ----
        float fa = 0.f, fb = 0.f, fc = 0.f, fd = 0.f;
        float x0 = 0.f, x1 = 0.f, x2 = 0.f;
        float R00 = 0.f, R01 = 0.f, R10 = 0.f, R11 = 0.f;
        if (lane < 16 && n < N) {
            const f32x4 fv = ((const f32x4*)F)[n];
            fa = fv.x; fb = fv.y; fc = fv.z; fd = fv.w;
            const float J   = fa * fd - fb * fc;
            const float ss  = fa * fa + fb * fb + fc * fc + fd * fd;
            const float sgn = (J >= 0.f) ? 1.f : -1.f;
            const float r   = sqrtf(fmaxf(ss + 2.f * fabsf(J), 1e-30f));
            const float inv = 1.f / r;
            x0 = r - 2.f; x1 = ss - 1.f; x2 = J - 1.f;
            R00 = (fa + sgn * fd) * inv; R01 = (fb - sgn * fc) * inv;
            R10 = (fc - sgn * fb) * inv; R11 = (fd + sgn * fa) * inv;
        }
        // broadcast x of row lr to all lane groups
        const float xa0 = __shfl(x0, lr, 64);
        const float xa1 = __shfl(x1, lr, 64);
        const float xa2 = __shfl(x2, lr, 64);

        // ---- layer 2: h2^T = W2^T * h1^T (h1 built on the fly, 16 rows/wave) ----
        f32x4 acc_0 = {0.f,0.f,0.f,0.f}, acc_1 = {0.f,0.f,0.f,0.f},
              acc_2 = {0.f,0.f,0.f,0.f}, acc_3 = {0.f,0.f,0.f,0.f},
              acc_4 = {0.f,0.f,0.f,0.f}, acc_5 = {0.f,0.f,0.f,0.f},
              acc_6 = {0.f,0.f,0.f,0.f}, acc_7 = {0.f,0.f,0.f,0.f};

        #pragma unroll
        for (int ks = 0; ks < 4; ++ks) {
            const int q = 2 * g + 8 * ks;        // f32x4 index of k0 = 8g+32ks
            const f32x4 w0lo = pW1[q],      w0hi = pW1[q + 1];
            const f32x4 w1lo = pW1[32 + q], w1hi = pW1[32 + q + 1];
            const f32x4 w2lo = pW1[64 + q], w2hi = pW1[64 + q + 1];
            const f32x4 blo  = pB1[q],      bhi  = pB1[q + 1];

            const f32x4 hlo = relu4(blo + w0lo * xa0 + w1lo * xa1 + w2lo * xa2);
            const f32x4 hhi = relu4(bhi + w0hi * xa0 + w1hi * xa1 + w2hi * xa2);

            uint4v u;
            u.x = pk2bf(hlo.x, hlo.y); u.y = pk2bf(hlo.z, hlo.w);
            u.z = pk2bf(hhi.x, hhi.y); u.w = pk2bf(hhi.z, hhi.w);
            const short8v bf = __builtin_bit_cast(short8v, u);

            #define STEP(JT) acc_##JT = MFMA(__builtin_bit_cast(short8v, sA2[((JT) * 4 + ks) * 64 + lane]), bf, acc_##JT)
            STEP(0); STEP(1); STEP(2); STEP(3);
            STEP(4); STEP(5); STEP(6); STEP(7);
            #undef STEP
        }

        // ---- layer 3: y^T = W3^T * relu(h2 + b2), one MFMA chain ----
        f32x4 accY = {0.f, 0.f, 0.f, 0.f};
        #define L3(KS2, A, B) {                                                   \
            const f32x4 ba = pB2[g + 8 * (KS2)];                                  \
            const f32x4 bb = pB2[g + 8 * (KS2) + 4];                              \
            const f32x4 ha = relu4((A) + ba);                                     \
            const f32x4 hb = relu4((B) + bb);                                     \
            uint4v u;                                                             \
            u.x = pk2bf(ha.x, ha.y); u.y = pk2bf(ha.z, ha.w);                     \
            u.z = pk2bf(hb.x, hb.y); u.w = pk2bf(hb.z, hb.w);                     \
            accY = MFMA(__builtin_bit_cast(short8v, sA3[(KS2) * 64 + lane]),      \
                        __builtin_bit_cast(short8v, u), accY);                    \
        }
        L3(0, acc_0, acc_1); L3(1, acc_2, acc_3);
        L3(2, acc_4, acc_5); L3(3, acc_6, acc_7);
        #undef L3

        // ---- epilogue: lanes 0..15 hold y[0..3] of row n; F,R kept in regs ----
        if (lane < 16 && n < N) {
            const float y0 = accY.x, y1 = accY.y, y2 = accY.z, y3 = accY.w;
            const float s01 = 0.5f * (y1 + y2);
            const float P00 = R00 * y0  + R01 * s01;
            const float P01 = R00 * s01 + R01 * y3;
            const float P10 = R10 * y0  + R11 * s01;
            const float P11 = R10 * s01 + R11 * y3;
            f32x4 o;
            o.x = P00 * fa + P01 * fb;   // cauchy = P @ F^T
            o.y = P00 * fc + P01 * fd;
            o.z = P10 * fa + P11 * fb;
            o.w = P10 * fc + P11 * fd;
            ((f32x4*)out)[n] = o;
        }
    }
}

extern "C" void kernel_launch(void* const* d_in, const int* in_sizes, int n_in,
                              void* d_out, int out_size, void* d_ws, size_t ws_size,
                              hipStream_t stream) {
    const float* F  = (const float*)d_in[0];
    const float* W1 = (const float*)d_in[1];
    const float* b1 = (const float*)d_in[2];
    const float* W2 = (const float*)d_in[3];
    const float* b2 = (const float*)d_in[4];
    const float* W3 = (const float*)d_in[5];
    const float* b3 = (const float*)d_in[6];
    float* out = (float*)d_out;
    const int N = in_sizes[0] / 4;

    const int nTiles = (N + TROWS - 1) / TROWS;
    int grid = nTiles < NBLK ? nTiles : NBLK;
    stress_kernel<<<dim3(grid), dim3(TPB), 0, stream>>>(F, W1, b1, W2, b2, W3, b3, out, N);
}

// Round 5
// 348.802 us; speedup vs baseline: 1.9093x; 1.9093x over previous
//
#include <hip/hip_runtime.h>
#include <hip/hip_bf16.h>
#include <math.h>

#define HID   128
#define TPB   256      // 4 waves per block, 16 rows per wave -> 64 rows per block-tile
#define TROWS 64
#define NBLK  768      // persistent grid (~3 blocks/CU)

typedef __attribute__((ext_vector_type(8))) short        short8v;   // 8 bf16
typedef __attribute__((ext_vector_type(4))) float        f32x4;
typedef __attribute__((ext_vector_type(4))) unsigned int uint4v;

#define MFMA(a, b, c) __builtin_amdgcn_mfma_f32_16x16x32_bf16((a), (b), (c), 0, 0, 0)

__device__ __forceinline__ unsigned int pk2bf(float lo, float hi) {
    unsigned short a = __builtin_bit_cast(unsigned short, __float2bfloat16(lo));
    unsigned short b = __builtin_bit_cast(unsigned short, __float2bfloat16(hi));
    return (unsigned int)a | ((unsigned int)b << 16);
}
__device__ __forceinline__ f32x4 relu4(f32x4 v) {
    f32x4 r;
    r.x = fmaxf(v.x, 0.f); r.y = fmaxf(v.y, 0.f);
    r.z = fmaxf(v.z, 0.f); r.w = fmaxf(v.w, 0.f);
    return r;
}

// min 2 waves/EU -> 256-reg unified cap (~128 VGPR + 128 AGPR): fits the
// ~90-VGPR transient set + ~40 AGPR accumulators with NO scratch spills.
__global__ __launch_bounds__(TPB, 2)
void stress_kernel(const float* __restrict__ F,
                   const float* __restrict__ W1, const float* __restrict__ b1,
                   const float* __restrict__ W2, const float* __restrict__ b2,
                   const float* __restrict__ W3, const float* __restrict__ b3,
                   float* __restrict__ out, int N)
{
    // ---- LDS: constant, fragment-ordered weights (38.5 KB) ----
    __shared__ uint4v sA2[2048];   // 32 KB  W2^T A-frags: [(jt*4+ks)*64 + lane]
    __shared__ uint4v sA3[256];    //  4 KB  W3^T A-frags: [ks2*64 + lane]
    __shared__ __align__(16) float sW1[3 * HID];
    __shared__ __align__(16) float sb1[HID];
    __shared__ __align__(16) float sb2[HID];

    const int tid  = threadIdx.x;
    const int lane = tid & 63;
    const int wid  = tid >> 6;
    const int g    = lane >> 4;     // lane group 0..3
    const int lr   = lane & 15;

    // ---- one-time per-block weight staging / swizzling ----
    // A2: value(lane,b,ks,jt) = bf16( W2[k][j] ), k = 8g+b+32ks, j = lr+16jt
    for (int e = tid; e < 2048; e += TPB) {
        int l = e & 63, ks = (e >> 6) & 3, jt = e >> 8;
        int k0 = 8 * (l >> 4) + 32 * ks;
        int j  = (l & 15) + 16 * jt;
        uint4v v;
        v.x = pk2bf(W2[(k0 + 0) * HID + j], W2[(k0 + 1) * HID + j]);
        v.y = pk2bf(W2[(k0 + 2) * HID + j], W2[(k0 + 3) * HID + j]);
        v.z = pk2bf(W2[(k0 + 4) * HID + j], W2[(k0 + 5) * HID + j]);
        v.w = pk2bf(W2[(k0 + 6) * HID + j], W2[(k0 + 7) * HID + j]);
        sA2[e] = v;
    }
    // A3: row t = lr (pad t>=4 with 0), slot (g,b,ks2) -> j = 4g+(b&3)+16*(2ks2+(b>>2))
    for (int e = tid; e < 256; e += TPB) {
        int l = e & 63, ks2 = e >> 6;
        int gg = l >> 4, t = l & 15;
        float w0  = (t < 4) ? W3[(4 * gg + 0 + 16 * (2 * ks2 + 0)) * 4 + t] : 0.f;
        float w1_ = (t < 4) ? W3[(4 * gg + 1 + 16 * (2 * ks2 + 0)) * 4 + t] : 0.f;
        float w2_ = (t < 4) ? W3[(4 * gg + 2 + 16 * (2 * ks2 + 0)) * 4 + t] : 0.f;
        float w3_ = (t < 4) ? W3[(4 * gg + 3 + 16 * (2 * ks2 + 0)) * 4 + t] : 0.f;
        float w4  = (t < 4) ? W3[(4 * gg + 0 + 16 * (2 * ks2 + 1)) * 4 + t] : 0.f;
        float w5  = (t < 4) ? W3[(4 * gg + 1 + 16 * (2 * ks2 + 1)) * 4 + t] : 0.f;
        float w6  = (t < 4) ? W3[(4 * gg + 2 + 16 * (2 * ks2 + 1)) * 4 + t] : 0.f;
        float w7  = (t < 4) ? W3[(4 * gg + 3 + 16 * (2 * ks2 + 1)) * 4 + t] : 0.f;
        uint4v v;
        v.x = pk2bf(w0, w1_); v.y = pk2bf(w2_, w3_);
        v.z = pk2bf(w4, w5);  v.w = pk2bf(w6, w7);
        sA3[e] = v;
    }
    for (int i = tid; i < 3 * HID; i += TPB) sW1[i] = W1[i];
    for (int i = tid; i < HID; i += TPB)     { sb1[i] = b1[i]; sb2[i] = b2[i]; }
    __syncthreads();

    // typed LDS vector views
    const f32x4* pW1 = (const f32x4*)sW1;   // pW1[i*32 + k/4] = W1[i][k..k+3]
    const f32x4* pB1 = (const f32x4*)sb1;
    const f32x4* pB2 = (const f32x4*)sb2;

    const int nTiles = (N + TROWS - 1) / TROWS;
    for (int tile = blockIdx.x; tile < nTiles; tile += gridDim.x) {
        const int n = tile * TROWS + wid * 16 + lr;   // row owned by lanes 0..15 (g==0)

        // ---- prologue: lanes 0..15 load F, compute invariants + polar R ----
        float fa = 0.f, fb = 0.f, fc = 0.f, fd = 0.f;
        float x0 = 0.f, x1 = 0.f, x2 = 0.f;
        float R00 = 0.f, R01 = 0.f, R10 = 0.f, R11 = 0.f;
        if (lane < 16 && n < N) {
            const f32x4 fv = ((const f32x4*)F)[n];
            fa = fv.x; fb = fv.y; fc = fv.z; fd = fv.w;
            const float J   = fa * fd - fb * fc;
            const float ss  = fa * fa + fb * fb + fc * fc + fd * fd;
            const float sgn = (J >= 0.f) ? 1.f : -1.f;
            const float r   = sqrtf(fmaxf(ss + 2.f * fabsf(J), 1e-30f));
            const float inv = 1.f / r;
            x0 = r - 2.f; x1 = ss - 1.f; x2 = J - 1.f;
            R00 = (fa + sgn * fd) * inv; R01 = (fb - sgn * fc) * inv;
            R10 = (fc - sgn * fb) * inv; R11 = (fd + sgn * fa) * inv;
        }
        // broadcast x of row lr to all lane groups
        const float xa0 = __shfl(x0, lr, 64);
        const float xa1 = __shfl(x1, lr, 64);
        const float xa2 = __shfl(x2, lr, 64);

        // ---- layer 2: h2^T = W2^T * h1^T (h1 built on the fly, 16 rows/wave) ----
        f32x4 acc_0 = {0.f,0.f,0.f,0.f}, acc_1 = {0.f,0.f,0.f,0.f},
              acc_2 = {0.f,0.f,0.f,0.f}, acc_3 = {0.f,0.f,0.f,0.f},
              acc_4 = {0.f,0.f,0.f,0.f}, acc_5 = {0.f,0.f,0.f,0.f},
              acc_6 = {0.f,0.f,0.f,0.f}, acc_7 = {0.f,0.f,0.f,0.f};

        #pragma unroll
        for (int ks = 0; ks < 4; ++ks) {
            const int q = 2 * g + 8 * ks;        // f32x4 index of k0 = 8g+32ks
            const f32x4 w0lo = pW1[q],      w0hi = pW1[q + 1];
            const f32x4 w1lo = pW1[32 + q], w1hi = pW1[32 + q + 1];
            const f32x4 w2lo = pW1[64 + q], w2hi = pW1[64 + q + 1];
            const f32x4 blo  = pB1[q],      bhi  = pB1[q + 1];

            const f32x4 hlo = relu4(blo + w0lo * xa0 + w1lo * xa1 + w2lo * xa2);
            const f32x4 hhi = relu4(bhi + w0hi * xa0 + w1hi * xa1 + w2hi * xa2);

            uint4v u;
            u.x = pk2bf(hlo.x, hlo.y); u.y = pk2bf(hlo.z, hlo.w);
            u.z = pk2bf(hhi.x, hhi.y); u.w = pk2bf(hhi.z, hhi.w);
            const short8v bf = __builtin_bit_cast(short8v, u);

            #define STEP(JT) acc_##JT = MFMA(__builtin_bit_cast(short8v, sA2[((JT) * 4 + ks) * 64 + lane]), bf, acc_##JT)
            STEP(0); STEP(1); STEP(2); STEP(3);
            STEP(4); STEP(5); STEP(6); STEP(7);
            #undef STEP
        }

        // ---- layer 3: y^T = W3^T * relu(h2 + b2), one MFMA chain ----
        f32x4 accY = {0.f, 0.f, 0.f, 0.f};
        #define L3(KS2, A, B) {                                                   \
            const f32x4 ba = pB2[g + 8 * (KS2)];                                  \
            const f32x4 bb = pB2[g + 8 * (KS2) + 4];                              \
            const f32x4 ha = relu4((A) + ba);                                     \
            const f32x4 hb = relu4((B) + bb);                                     \
            uint4v u;                                                             \
            u.x = pk2bf(ha.x, ha.y); u.y = pk2bf(ha.z, ha.w);                     \
            u.z = pk2bf(hb.x, hb.y); u.w = pk2bf(hb.z, hb.w);                     \
            accY = MFMA(__builtin_bit_cast(short8v, sA3[(KS2) * 64 + lane]),      \
                        __builtin_bit_cast(short8v, u), accY);                    \
        }
        L3(0, acc_0, acc_1); L3(1, acc_2, acc_3);
        L3(2, acc_4, acc_5); L3(3, acc_6, acc_7);
        #undef L3

        // ---- epilogue: lanes 0..15 hold y[0..3] of row n; F,R kept in regs ----
        if (lane < 16 && n < N) {
            const float y0 = accY.x, y1 = accY.y, y2 = accY.z, y3 = accY.w;
            const float s01 = 0.5f * (y1 + y2);
            const float P00 = R00 * y0  + R01 * s01;
            const float P01 = R00 * s01 + R01 * y3;
            const float P10 = R10 * y0  + R11 * s01;
            const float P11 = R10 * s01 + R11 * y3;
            f32x4 o;
            o.x = P00 * fa + P01 * fb;   // cauchy = P @ F^T
            o.y = P00 * fc + P01 * fd;
            o.z = P10 * fa + P11 * fb;
            o.w = P10 * fc + P11 * fd;
            ((f32x4*)out)[n] = o;
        }
    }
}

extern "C" void kernel_launch(void* const* d_in, const int* in_sizes, int n_in,
                              void* d_out, int out_size, void* d_ws, size_t ws_size,
                              hipStream_t stream) {
    const float* F  = (const float*)d_in[0];
    const float* W1 = (const float*)d_in[1];
    const float* b1 = (const float*)d_in[2];
    const float* W2 = (const float*)d_in[3];
    const float* b2 = (const float*)d_in[4];
    const float* W3 = (const float*)d_in[5];
    const float* b3 = (const float*)d_in[6];
    float* out = (float*)d_out;
    const int N = in_sizes[0] / 4;

    const int nTiles = (N + TROWS - 1) / TROWS;
    int grid = nTiles < NBLK ? nTiles : NBLK;
    stress_kernel<<<dim3(grid), dim3(TPB), 0, stream>>>(F, W1, b1, W2, b2, W3, b3, out, N);
}

// Round 6
// 70.724 us; speedup vs baseline: 9.4166x; 4.9319x over previous
//
#include <hip/hip_runtime.h>
#include <hip/hip_bf16.h>
#include <math.h>

#define HID   128
#define TPB   256      // 4 waves per block, 16 rows per wave -> 64 rows per block-tile
#define TROWS 64
#define NBLK  768      // persistent grid

typedef __attribute__((ext_vector_type(8))) short        short8v;   // 8 bf16
typedef __attribute__((ext_vector_type(4))) float        f32x4;
typedef __attribute__((ext_vector_type(4))) unsigned int uint4v;

#define MFMA(a, b, c) __builtin_amdgcn_mfma_f32_16x16x32_bf16((a), (b), (c), 0, 0, 0)
#define SCHED_FENCE() __builtin_amdgcn_sched_barrier(0)

__device__ __forceinline__ unsigned int pk2bf(float lo, float hi) {
    unsigned short a = __builtin_bit_cast(unsigned short, __float2bfloat16(lo));
    unsigned short b = __builtin_bit_cast(unsigned short, __float2bfloat16(hi));
    return (unsigned int)a | ((unsigned int)b << 16);
}
__device__ __forceinline__ f32x4 relu4(f32x4 v) {
    f32x4 r;
    r.x = fmaxf(v.x, 0.f); r.y = fmaxf(v.y, 0.f);
    r.z = fmaxf(v.z, 0.f); r.w = fmaxf(v.w, 0.f);
    return r;
}

__global__ __launch_bounds__(TPB, 2)
void stress_kernel(const float* __restrict__ F,
                   const float* __restrict__ W1, const float* __restrict__ b1,
                   const float* __restrict__ W2, const float* __restrict__ b2,
                   const float* __restrict__ W3, const float* __restrict__ b3,
                   float* __restrict__ out, int N)
{
    // ---- LDS: constant, fragment-ordered weights (38.5 KB) ----
    __shared__ uint4v sA2[2048];   // 32 KB  W2^T A-frags: [(jt*4+ks)*64 + lane]
    __shared__ uint4v sA3[256];    //  4 KB  W3^T A-frags: [ks2*64 + lane]
    __shared__ __align__(16) float sW1[3 * HID];
    __shared__ __align__(16) float sb1[HID];
    __shared__ __align__(16) float sb2[HID];

    const int tid  = threadIdx.x;
    const int lane = tid & 63;
    const int wid  = tid >> 6;
    const int g    = lane >> 4;     // lane group 0..3
    const int lr   = lane & 15;

    // ---- one-time per-block weight staging / swizzling ----
    for (int e = tid; e < 2048; e += TPB) {
        int l = e & 63, ks = (e >> 6) & 3, jt = e >> 8;
        int k0 = 8 * (l >> 4) + 32 * ks;
        int j  = (l & 15) + 16 * jt;
        uint4v v;
        v.x = pk2bf(W2[(k0 + 0) * HID + j], W2[(k0 + 1) * HID + j]);
        v.y = pk2bf(W2[(k0 + 2) * HID + j], W2[(k0 + 3) * HID + j]);
        v.z = pk2bf(W2[(k0 + 4) * HID + j], W2[(k0 + 5) * HID + j]);
        v.w = pk2bf(W2[(k0 + 6) * HID + j], W2[(k0 + 7) * HID + j]);
        sA2[e] = v;
    }
    for (int e = tid; e < 256; e += TPB) {
        int l = e & 63, ks2 = e >> 6;
        int gg = l >> 4, t = l & 15;
        float w0  = (t < 4) ? W3[(4 * gg + 0 + 16 * (2 * ks2 + 0)) * 4 + t] : 0.f;
        float w1_ = (t < 4) ? W3[(4 * gg + 1 + 16 * (2 * ks2 + 0)) * 4 + t] : 0.f;
        float w2_ = (t < 4) ? W3[(4 * gg + 2 + 16 * (2 * ks2 + 0)) * 4 + t] : 0.f;
        float w3_ = (t < 4) ? W3[(4 * gg + 3 + 16 * (2 * ks2 + 0)) * 4 + t] : 0.f;
        float w4  = (t < 4) ? W3[(4 * gg + 0 + 16 * (2 * ks2 + 1)) * 4 + t] : 0.f;
        float w5  = (t < 4) ? W3[(4 * gg + 1 + 16 * (2 * ks2 + 1)) * 4 + t] : 0.f;
        float w6  = (t < 4) ? W3[(4 * gg + 2 + 16 * (2 * ks2 + 1)) * 4 + t] : 0.f;
        float w7  = (t < 4) ? W3[(4 * gg + 3 + 16 * (2 * ks2 + 1)) * 4 + t] : 0.f;
        uint4v v;
        v.x = pk2bf(w0, w1_); v.y = pk2bf(w2_, w3_);
        v.z = pk2bf(w4, w5);  v.w = pk2bf(w6, w7);
        sA3[e] = v;
    }
    for (int i = tid; i < 3 * HID; i += TPB) sW1[i] = W1[i];
    for (int i = tid; i < HID; i += TPB)     { sb1[i] = b1[i]; sb2[i] = b2[i]; }
    __syncthreads();

    // typed LDS vector views
    const f32x4* pW1 = (const f32x4*)sW1;   // pW1[i*32 + k/4] = W1[i][k..k+3]
    const f32x4* pB1 = (const f32x4*)sb1;
    const f32x4* pB2 = (const f32x4*)sb2;

    const int nTiles = (N + TROWS - 1) / TROWS;
    for (int tile = blockIdx.x; tile < nTiles; tile += gridDim.x) {
        const int n = tile * TROWS + wid * 16 + lr;   // row owned by lanes 0..15

        // ---- prologue: lanes 0..15 load F, compute invariants + polar R ----
        float fa = 0.f, fb = 0.f, fc = 0.f, fd = 0.f;
        float x0 = 0.f, x1 = 0.f, x2 = 0.f;
        float R00 = 0.f, R01 = 0.f, R10 = 0.f, R11 = 0.f;
        if (lane < 16 && n < N) {
            const f32x4 fv = ((const f32x4*)F)[n];
            fa = fv.x; fb = fv.y; fc = fv.z; fd = fv.w;
            const float J   = fa * fd - fb * fc;
            const float ss  = fa * fa + fb * fb + fc * fc + fd * fd;
            const float sgn = (J >= 0.f) ? 1.f : -1.f;
            const float r   = sqrtf(fmaxf(ss + 2.f * fabsf(J), 1e-30f));
            const float inv = 1.f / r;
            x0 = r - 2.f; x1 = ss - 1.f; x2 = J - 1.f;
            R00 = (fa + sgn * fd) * inv; R01 = (fb - sgn * fc) * inv;
            R10 = (fc - sgn * fb) * inv; R11 = (fd + sgn * fa) * inv;
        }
        const float xa0 = __shfl(x0, lr, 64);
        const float xa1 = __shfl(x1, lr, 64);
        const float xa2 = __shfl(x2, lr, 64);
        SCHED_FENCE();

        // ---- Phase 1: build all four layer-2 B-fragments (h1, on the fly) ----
        short8v bfr_0, bfr_1, bfr_2, bfr_3;
        #define HCOMP(KS, DST) {                                                  \
            const int q = 2 * g + 8 * (KS);                                       \
            const f32x4 w0lo = pW1[q],      w0hi = pW1[q + 1];                    \
            const f32x4 w1lo = pW1[32 + q], w1hi = pW1[32 + q + 1];               \
            const f32x4 w2lo = pW1[64 + q], w2hi = pW1[64 + q + 1];               \
            const f32x4 blo  = pB1[q],      bhi  = pB1[q + 1];                    \
            const f32x4 hlo = relu4(blo + w0lo * xa0 + w1lo * xa1 + w2lo * xa2);  \
            const f32x4 hhi = relu4(bhi + w0hi * xa0 + w1hi * xa1 + w2hi * xa2);  \
            uint4v u;                                                             \
            u.x = pk2bf(hlo.x, hlo.y); u.y = pk2bf(hlo.z, hlo.w);                 \
            u.z = pk2bf(hhi.x, hhi.y); u.w = pk2bf(hhi.z, hhi.w);                 \
            DST = __builtin_bit_cast(short8v, u);                                 \
        } SCHED_FENCE();
        HCOMP(0, bfr_0) HCOMP(1, bfr_1) HCOMP(2, bfr_2) HCOMP(3, bfr_3)
        #undef HCOMP

        // ---- Phase 2: layer-2 MFMA, 4 groups of 8 (caps in-flight A-frags) ----
        f32x4 acc_0 = {0.f,0.f,0.f,0.f}, acc_1 = {0.f,0.f,0.f,0.f},
              acc_2 = {0.f,0.f,0.f,0.f}, acc_3 = {0.f,0.f,0.f,0.f},
              acc_4 = {0.f,0.f,0.f,0.f}, acc_5 = {0.f,0.f,0.f,0.f},
              acc_6 = {0.f,0.f,0.f,0.f}, acc_7 = {0.f,0.f,0.f,0.f};

        #define STEP(JT, KS, BF) acc_##JT = MFMA(__builtin_bit_cast(short8v, sA2[((JT) * 4 + (KS)) * 64 + lane]), BF, acc_##JT)
        #define KSGROUP(KS, BF) {                                                 \
            STEP(0, KS, BF); STEP(1, KS, BF); STEP(2, KS, BF); STEP(3, KS, BF);   \
            STEP(4, KS, BF); STEP(5, KS, BF); STEP(6, KS, BF); STEP(7, KS, BF);   \
        } SCHED_FENCE();
        KSGROUP(0, bfr_0) KSGROUP(1, bfr_1) KSGROUP(2, bfr_2) KSGROUP(3, bfr_3)
        #undef KSGROUP
        #undef STEP

        // ---- Phase 3: layer 3 (one MFMA chain) ----
        f32x4 accY = {0.f, 0.f, 0.f, 0.f};
        #define L3(KS2, A, B) {                                                   \
            const f32x4 ba = pB2[g + 8 * (KS2)];                                  \
            const f32x4 bb = pB2[g + 8 * (KS2) + 4];                              \
            const f32x4 ha = relu4((A) + ba);                                     \
            const f32x4 hb = relu4((B) + bb);                                     \
            uint4v u;                                                             \
            u.x = pk2bf(ha.x, ha.y); u.y = pk2bf(ha.z, ha.w);                     \
            u.z = pk2bf(hb.x, hb.y); u.w = pk2bf(hb.z, hb.w);                     \
            accY = MFMA(__builtin_bit_cast(short8v, sA3[(KS2) * 64 + lane]),      \
                        __builtin_bit_cast(short8v, u), accY);                    \
        } SCHED_FENCE();
        L3(0, acc_0, acc_1) L3(1, acc_2, acc_3)
        L3(2, acc_4, acc_5) L3(3, acc_6, acc_7)
        #undef L3

        // ---- epilogue: lanes 0..15 hold y[0..3] of row n; F,R kept in regs ----
        if (lane < 16 && n < N) {
            const float y0 = accY.x, y1 = accY.y, y2 = accY.z, y3 = accY.w;
            const float s01 = 0.5f * (y1 + y2);
            const float P00 = R00 * y0  + R01 * s01;
            const float P01 = R00 * s01 + R01 * y3;
            const float P10 = R10 * y0  + R11 * s01;
            const float P11 = R10 * s01 + R11 * y3;
            f32x4 o;
            o.x = P00 * fa + P01 * fb;   // cauchy = P @ F^T
            o.y = P00 * fc + P01 * fd;
            o.z = P10 * fa + P11 * fb;
            o.w = P10 * fc + P11 * fd;
            ((f32x4*)out)[n] = o;
        }
    }
}

extern "C" void kernel_launch(void* const* d_in, const int* in_sizes, int n_in,
                              void* d_out, int out_size, void* d_ws, size_t ws_size,
                              hipStream_t stream) {
    const float* F  = (const float*)d_in[0];
    const float* W1 = (const float*)d_in[1];
    const float* b1 = (const float*)d_in[2];
    const float* W2 = (const float*)d_in[3];
    const float* b2 = (const float*)d_in[4];
    const float* W3 = (const float*)d_in[5];
    const float* b3 = (const float*)d_in[6];
    float* out = (float*)d_out;
    const int N = in_sizes[0] / 4;

    const int nTiles = (N + TROWS - 1) / TROWS;
    int grid = nTiles < NBLK ? nTiles : NBLK;
    stress_kernel<<<dim3(grid), dim3(TPB), 0, stream>>>(F, W1, b1, W2, b2, W3, b3, out, N);
}